// Round 9
// baseline (230.416 us; speedup 1.0000x reference)
//
#include <hip/hip_runtime.h>

// ============================================================================
// global_conv_attn: B=4, C=H=O=256, N=4096, GROUPS=32
//
// Pipeline (all bf16-MFMA, fp32 accumulate), 4 launches:
//   prepW : weights fp32->bf16 (256 blocks, ~1us)
//   fused1: gemm1 + conv + gemm2 FUSED. Block = (b, 32n). v1 NEVER touches
//           HBM (34MB write + 34MB read saved). Halo via second shifted
//           MFMA window: wave roles kind=wv: w0=k, w1=q, w2=v1[cols 0..31],
//           w3=v1[cols 2..33] (overlap writes bit-identical values).
//           xL[34] staged cols n032-1..n032+32; edge blocks zero v1L 0/33
//           to reproduce conv zero-pad. conv reads v1L[n][h] as b128
//           (8-lane broadcast, conflict-free); gemm2 as before.
//           k CHUNK-TILED store bit-compatible with attn.
//   attn  : flash, 32x32x16 MFMA, m32/wave, 8 waves/block (512 thr, 256
//           blks), K ring x3 + V ring x4 (112KB), counted vmcnt, wave-group
//           stagger; pacc bf16 partials + pml. AT PLATEAU (4 schedule
//           variants neutral 74->71us; sum-of-pipes wall, reg-pinned).
//   comb  : merge of 4 splits (~8us)
//
// R15 post-mortem: op-split gemm1 WON -18.8us (more than predicted: also
// removed duplicated W traffic + x restage across h-halves). Budget:
// kernels ~102us (attn 71 + gemm1 11 + cg2 ~10 + comb 8 + prep 2).
// R16 fuses gemm1+cg2: the conv halo (blocker) is computed locally via a
// +33% duplicated v1 MFMA window -- cheaper than 68MB of HBM round-trip.
// All f2bf chains and MFMA accumulation orders identical -> absmax must
// hold at 4.88e-4 exactly (any change = halo indexing bug).
//
// MFMA 32x32x16 layouts (gfx950):
//   A row=lane&31, k=(lane>>5)*8+j;  B col=lane&31, same k
//   D col=lane&31, row=(reg&3)+8*(reg>>2)+4*(lane>>5)   [D HW-verified]
// ============================================================================

#define B_ 4
#define C_ 256
#define H_ 256
#define O_ 256
#define N_ 4096
#define NSPLIT 4
#define SPAN (N_ / NSPLIT)     // 1024
#define ITERS (SPAN / 32)      // 32

typedef short short8 __attribute__((ext_vector_type(8)));
typedef float floatx4 __attribute__((ext_vector_type(4)));
typedef float floatx16 __attribute__((ext_vector_type(16)));
typedef unsigned uint2v __attribute__((ext_vector_type(2)));

__device__ __forceinline__ unsigned short f2bf(float f) {
  unsigned u = __float_as_uint(f);
  u = (u + 0x7fffu + ((u >> 16) & 1u)) >> 16;   // RNE
  return (unsigned short)u;
}
__device__ __forceinline__ float bf2f(unsigned short u) {
  return __uint_as_float(((unsigned)u) << 16);
}
__device__ __forceinline__ floatx16 mfma32(short8 a, short8 b, floatx16 c) {
  return __builtin_amdgcn_mfma_f32_32x32x16_bf16(a, b, c, 0, 0, 0);
}
// pack two floats -> (bf16(a) | bf16(b)<<16), round-half-up (2 add + 1 perm)
__device__ __forceinline__ unsigned pack2bf(float a, float b) {
  return __builtin_amdgcn_perm(__float_as_uint(b) + 0x8000u,
                               __float_as_uint(a) + 0x8000u, 0x07060302u);
}

// ---------------------------------------------------------------------------
// weight prep: fp32 -> bf16 for Wk,Wq,W1 (contiguous) and W3.
__global__ __launch_bounds__(256) void prep_w_kernel(
    const float* __restrict__ Wk, const float* __restrict__ Wq,
    const float* __restrict__ W1, const float* __restrict__ W3,
    unsigned short* __restrict__ wk, unsigned short* __restrict__ wq,
    unsigned short* __restrict__ w1, unsigned short* __restrict__ w3) {
  const int i = blockIdx.x * 256 + threadIdx.x;    // 65536
  wk[i] = f2bf(Wk[i]);
  wq[i] = f2bf(Wq[i]);
  w1[i] = f2bf(W1[i]);
  w3[i] = f2bf(W3[i]);
}

// ---------------------------------------------------------------------------
// fused1: gemm1(k,q,v1) + grouped conv + gemm2 in one kernel.
// Block (512 total) = (b, nc32). 4 waves, 8 units each.
// xL rows: 0 = n032-1 (halo), 1..32 = main cols, 33 = n032+32 (halo).
// Wave kind = wv: 0 -> k (A-base row 1), 1 -> q (base 1),
//                 2 -> v1 window A cols 0..31 (base 0),
//                 3 -> v1 window B cols 2..33 (base 2).
// v1 -> v1L[34][264] in LDS only (bf16, same f2bf as before).
__global__ __launch_bounds__(256) void fused1_kernel(
    const float* __restrict__ x,
    const unsigned short* __restrict__ wk,   // wk|wq|w1 contiguous
    const float* __restrict__ bk, const float* __restrict__ bq,
    const float* __restrict__ b1,
    const float* __restrict__ W2, const float* __restrict__ b2,
    const unsigned short* __restrict__ w3, const float* __restrict__ b3,
    unsigned short* __restrict__ ko, unsigned short* __restrict__ qo,
    unsigned short* __restrict__ vo) {
  __shared__ unsigned short xL[34][264];    // 18 KB
  __shared__ unsigned short v1L[34][264];   // 18 KB
  __shared__ unsigned short v2L[32][264];   // 17 KB

  const int blk  = blockIdx.x;     // 512
  const int b    = blk >> 7;
  const int nc   = blk & 127;
  const int n032 = nc * 32;
  const int t    = threadIdx.x;

  // stage main 32 cols -> xL rows 1..32 (coalesced floatx4 along n)
  {
    const int c0 = t >> 3;
    const int nq = t & 7;
    const float* xb = x + ((size_t)b * C_) * N_ + n032 + nq * 4;
#pragma unroll
    for (int i = 0; i < 8; ++i) {
      const int c = c0 + i * 32;
      const floatx4 v = *reinterpret_cast<const floatx4*>(xb + (size_t)c * N_);
#pragma unroll
      for (int j = 0; j < 4; ++j) xL[1 + nq * 4 + j][c] = f2bf(v[j]);
    }
  }
  // stage halo cols (scalar; L2-resident, 2KB/block)
  {
    const int c = t;
    const float lv =
        (n032 == 0) ? 0.f : x[((size_t)(b * C_ + c)) * N_ + n032 - 1];
    const float rv =
        (n032 + 32 >= N_) ? 0.f : x[((size_t)(b * C_ + c)) * N_ + n032 + 32];
    xL[0][c] = f2bf(lv);
    xL[33][c] = f2bf(rv);
  }
  __syncthreads();

  const int ln  = t & 63;
  const int wv  = t >> 6;      // 0..3 = kind
  const int m32 = ln & 31;
  const int hl  = ln >> 5;

  {
    // per-wave: op for weights, A-frag base row, bias
    const int op    = (wv <= 1) ? wv : 2;
    const int abase = (wv <= 1) ? 1 : ((wv == 2) ? 0 : 2);
    const float* bp = (op == 0) ? bk : ((op == 1) ? bq : b1);

    float ubias[8];
    int   uoff[8];
#pragma unroll
    for (int u = 0; u < 8; ++u) {
      uoff[u]  = op * 65536 + (u * 32 + m32) * 256 + hl * 8;
      ubias[u] = bp[u * 32 + m32];
    }

    floatx16 acc[8];
#pragma unroll
    for (int u = 0; u < 8; ++u)
#pragma unroll
      for (int r = 0; r < 16; ++r) acc[u][r] = 0.f;

#pragma unroll
    for (int ks = 0; ks < 16; ++ks) {
      short8 af =
          *reinterpret_cast<const short8*>(&xL[abase + m32][ks * 16 + hl * 8]);
#pragma unroll
      for (int u = 0; u < 8; ++u) {
        short8 bf = *reinterpret_cast<const short8*>(wk + uoff[u] + ks * 16);
        acc[u] = mfma32(af, bf, acc[u]);
      }
    }

    // stores by kind (wave-uniform branch)
    if (wv == 0) {
      // k chunk-tiled: elem = (h>>4)*512 + ((h>>3)&1)*256 + nl*8 + (h&7)
      unsigned short* kb = ko + ((size_t)(b * 128 + nc)) * 8192;
#pragma unroll
      for (int u = 0; u < 8; ++u) {
        const int h = u * 32 + m32;
        const int eh = (h >> 4) * 512 + ((h >> 3) & 1) * 256 + (h & 7);
#pragma unroll
        for (int r = 0; r < 16; ++r) {
          const int nl = (r & 3) + 8 * (r >> 2) + 4 * hl;
          kb[eh + nl * 8] = f2bf(acc[u][r] + ubias[u]);
        }
      }
    } else if (wv == 1) {
#pragma unroll
      for (int u = 0; u < 8; ++u) {
        const int h = u * 32 + m32;
#pragma unroll
        for (int r = 0; r < 16; ++r) {
          const int n = n032 + (r & 3) + 8 * (r >> 2) + 4 * hl;
          qo[((size_t)(b * N_ + n)) * H_ + h] = f2bf(acc[u][r] + ubias[u]);
        }
      }
    } else {
      // v1 windows -> v1L. winA (wv==2): col = crow; winB: col = crow+2.
      // Overlap cols 2..31 written twice with bit-identical values (benign).
      const int cofs = (wv == 2) ? 0 : 2;
#pragma unroll
      for (int u = 0; u < 8; ++u) {
        const int h = u * 32 + m32;
#pragma unroll
        for (int r = 0; r < 16; ++r) {
          const int col = cofs + (r & 3) + 8 * (r >> 2) + 4 * hl;
          v1L[col][h] = f2bf(acc[u][r] + ubias[u]);
        }
      }
    }
  }
  __syncthreads();

  // conv zero-pad boundaries (edge blocks only; matches lax 'SAME' pad)
  if (n032 == 0) v1L[0][t] = 0;
  if (n032 + 32 >= N_) v1L[33][t] = 0;
  __syncthreads();

  {  // conv: thread = h; v1L col c corresponds to n = n032 - 1 + c
    const int h  = t;
    const int g8 = h & ~7;
    float w[24];
#pragma unroll
    for (int i = 0; i < 24; ++i) w[i] = W2[h * 24 + i];
    const float bias = b2[h];

    float fp[8], fc[8], fn[8];
    {
      short8 u0 = *reinterpret_cast<const short8*>(&v1L[0][g8]);
      short8 u1 = *reinterpret_cast<const short8*>(&v1L[1][g8]);
#pragma unroll
      for (int i = 0; i < 8; ++i) {
        fp[i] = bf2f((unsigned short)u0[i]);
        fc[i] = bf2f((unsigned short)u1[i]);
      }
    }
#pragma unroll 1
    for (int ns = 0; ns < 32; ++ns) {
      short8 un = *reinterpret_cast<const short8*>(&v1L[ns + 2][g8]);
#pragma unroll
      for (int i = 0; i < 8; ++i) fn[i] = bf2f((unsigned short)un[i]);
      float a = bias;
#pragma unroll
      for (int i = 0; i < 8; ++i)
        a += w[i * 3] * fp[i] + w[i * 3 + 1] * fc[i] + w[i * 3 + 2] * fn[i];
      v2L[ns][h] = f2bf(fmaxf(a, 0.f));
#pragma unroll
      for (int i = 0; i < 8; ++i) { fp[i] = fc[i]; fc[i] = fn[i]; }
    }
  }
  __syncthreads();

  {  // gemm2: wave wv handles o-range wv*64..+63. A = W3 rows o, B = v2L.
    const int m  = m32;
    floatx16 acc2[2];
#pragma unroll
    for (int ot = 0; ot < 2; ++ot)
#pragma unroll
      for (int r = 0; r < 16; ++r) acc2[ot][r] = 0.f;

#pragma unroll
    for (int ks = 0; ks < 16; ++ks) {
      short8 bfr = *reinterpret_cast<const short8*>(&v2L[m][ks * 16 + hl * 8]);
#pragma unroll
      for (int ot = 0; ot < 2; ++ot) {
        const int o0 = wv * 64 + ot * 32;
        short8 afr = *reinterpret_cast<const short8*>(
            w3 + (o0 + m) * H_ + ks * 16 + hl * 8);
        acc2[ot] = mfma32(afr, bfr, acc2[ot]);
      }
    }

    // linear-lane chunk-tiled V store:
    // elem-in-kn-block = (o>>5)*512 + ((n&15)>>3)*256 + (o&31)*8 + (n&7)
    const int kn = (m >> 4) & 1;
    const int nl = m & 15;
    unsigned short* vkn = vo + ((size_t)(b * 128 + nc) * 2 + kn) * 4096;
#pragma unroll
    for (int ot = 0; ot < 2; ++ot)
#pragma unroll
      for (int r = 0; r < 16; ++r) {
        const int o = wv * 64 + ot * 32 + (r & 3) + 8 * (r >> 2) + 4 * hl;
        vkn[(o >> 5) * 512 + (nl >> 3) * 256 + (o & 31) * 8 + (nl & 7)] =
            f2bf(acc2[ot][r] + b3[o]);
      }
  }
}

// ---------------------------------------------------------------------------
// attn: m32/wave, 8 waves (512 thr) share staged K/V chunks, 256 blocks.
// K ring x3 + V ring x4 (112 KB), 2-chunk prefetch, counted vmcnt(4) + raw
// s_barrier (vmcnt(0) only at last). Wave-group stagger (grpA QK->SM->PV;
// grpB PV(prev)->QK->SM). Epilogue: normalized bf16 partials (pacc) + L.
__global__ __launch_bounds__(512, 2) void attn_kernel(
    const unsigned short* __restrict__ kbf, const unsigned short* __restrict__ qbf,
    const unsigned short* __restrict__ vbf,
    unsigned short* __restrict__ pacc, float* __restrict__ pml) {
  __shared__ __attribute__((aligned(16))) char smem[7][16384];   // 112 KB

  const int tid = threadIdx.x;
  const int ln  = tid & 63;
  const int wv  = tid >> 6;            // 0..7
  const int gid = blockIdx.x;          // 256
  const int b   = gid & 3;             // low bits -> XCD spread of (b,s)
  const int s   = (gid >> 2) & 3;
  const int mt256 = gid >> 4;          // 0..15
  const int mt32  = mt256 * 8 + wv;    // 0..127
  const int m0  = mt32 * 32;
  const int m   = ln & 31;
  const int hl  = ln >> 5;
  const bool grpB = (wv >= 4);
  // linear-lane fragment base: granule (row,hl) pre-placed at byte
  // hl*512+row*16 in each 1KB block -> lane ln reads byte ln*16.
  const int lane_base = ln * 16;

  // Q frags: col m = lane&31, k = ks*16 + hl*8 + j
  const unsigned short* qrow = qbf + ((size_t)b * N_ + m0 + m) * H_ + hl * 8;
  short8 qf[16];
#pragma unroll
  for (int ks = 0; ks < 16; ++ks)
    qf[ks] = *reinterpret_cast<const short8*>(qrow + ks * 16);

  floatx16 acc[8];
#pragma unroll
  for (int t = 0; t < 8; ++t)
#pragma unroll
    for (int r = 0; r < 16; ++r) acc[t][r] = 0.f;
  float Lp = 0.f;

  const size_t row0 = (size_t)(b * 128 + s * 32);

  // stage chunk nc: K -> slot nc%3, V -> slot 3 + (nc&3).
  // 512 lanes x 2 x 16B covers 16 KB each of K and V -> 4 loads/lane/chunk.
  auto stage = [&](int nc) {
    const char* kg = (const char*)(kbf + (row0 + nc) * 8192);
    const char* vg = (const char*)(vbf + (row0 + nc) * 8192);
    char* lk = &smem[nc % 3][0];
    char* lv = &smem[3 + (nc & 3)][0];
#pragma unroll
    for (int j = 0; j < 2; ++j) {
      const int ofs = j * 8192 + tid * 16;
      __builtin_amdgcn_global_load_lds(
          (const __attribute__((address_space(1))) void*)(kg + ofs),
          (__attribute__((address_space(3))) void*)(lk + ofs), 16, 0, 0);
      __builtin_amdgcn_global_load_lds(
          (const __attribute__((address_space(1))) void*)(vg + ofs),
          (__attribute__((address_space(3))) void*)(lv + ofs), 16, 0, 0);
    }
  };

  short8 pf0, pf1;   // P fragments (loop-carried across iters for grpB)

  // QK: S tile 32n x 32m, A = K rows from LDS, B = qf
  auto qk = [&](const char* sk) -> floatx16 {
    floatx16 sacc;
#pragma unroll
    for (int r = 0; r < 16; ++r) sacc[r] = 0.f;
    __builtin_amdgcn_s_setprio(1);
#pragma unroll
    for (int ks = 0; ks < 16; ++ks) {
      short8 kf = *reinterpret_cast<const short8*>(sk + lane_base + ks * 1024);
      sacc = mfma32(kf, qf[ks], sacc);
    }
    __builtin_amdgcn_s_setprio(0);
    return sacc;
  };
  // PV: D[o][m] += V-rows (A, from LDS) * P (B, regs)
  auto pv = [&](const char* sv) {
    __builtin_amdgcn_s_setprio(1);
#pragma unroll
    for (int ot = 0; ot < 8; ++ot) {
      short8 vf0 = *reinterpret_cast<const short8*>(sv + lane_base + ot * 1024);
      short8 vf1 = *reinterpret_cast<const short8*>(
          sv + lane_base + 8192 + ot * 1024);
      acc[ot] = mfma32(vf0, pf0, acc[ot]);
      acc[ot] = mfma32(vf1, pf1, acc[ot]);
    }
    __builtin_amdgcn_s_setprio(0);
  };
  // SM: P = exp(S), pack adjacent-n pairs, permlane32 relayout -> pf0/pf1
  auto softmax = [&](floatx16 sacc) {
#if __has_builtin(__builtin_amdgcn_permlane32_swap)
    unsigned d[8];
#pragma unroll
    for (int i = 0; i < 8; ++i) {
      const float a = __expf(sacc[2 * i]);
      const float bb = __expf(sacc[2 * i + 1]);
      Lp += a + bb;
      d[i] = pack2bf(a, bb);
    }
#pragma unroll
    for (int g = 0; g < 2; ++g) {
      uint2v r0 = __builtin_amdgcn_permlane32_swap(d[4 * g + 0], d[4 * g + 2],
                                                   false, false);
      uint2v r1 = __builtin_amdgcn_permlane32_swap(d[4 * g + 1], d[4 * g + 3],
                                                   false, false);
      d[4 * g + 0] = r0.x; d[4 * g + 2] = r0.y;
      d[4 * g + 1] = r1.x; d[4 * g + 3] = r1.y;
    }
    union { unsigned u[4]; short8 s8; } c0, c1;
    c0.u[0] = d[0]; c0.u[1] = d[1]; c0.u[2] = d[2]; c0.u[3] = d[3];
    c1.u[0] = d[4]; c1.u[1] = d[5]; c1.u[2] = d[6]; c1.u[3] = d[7];
    pf0 = c0.s8;
    pf1 = c1.s8;
#else
    // fallback: pack (r, r+4) pairs + 16 bpermute relayout (R6 path)
    float pv_[16];
#pragma unroll
    for (int r = 0; r < 16; ++r) { pv_[r] = __expf(sacc[r]); Lp += pv_[r]; }
    unsigned wpk[8];
#pragma unroll
    for (int r4 = 0; r4 < 4; ++r4) {
      wpk[r4]     = pack2bf(pv_[r4], pv_[r4 + 4]);
      wpk[r4 + 4] = pack2bf(pv_[r4 + 8], pv_[r4 + 12]);
    }
    const int hlsh = hl * 16;
#pragma unroll
    for (int j = 0; j < 8; ++j) {
      const int srcLane = m + ((j >> 2) << 5);
      const int u0 = __shfl((int)wpk[j & 3],       srcLane);
      const int u1 = __shfl((int)wpk[(j & 3) + 4], srcLane);
      pf0[j] = (short)((unsigned)u0 >> hlsh);
      pf1[j] = (short)((unsigned)u1 >> hlsh);
    }
#endif
  };

  stage(0);
  stage(1);

#pragma unroll 1
  for (int nc = 0; nc < ITERS; ++nc) {
    // counted drain: chunk nc landed; chunk nc+1's 4 loads may stay in
    // flight across the barrier. Full drain only on the last iter.
    if (nc + 1 < ITERS) {
      asm volatile("s_waitcnt vmcnt(4)\n\ts_barrier" ::: "memory");
    } else {
      asm volatile("s_waitcnt vmcnt(0)\n\ts_barrier" ::: "memory");
    }
    __builtin_amdgcn_sched_barrier(0);
    if (nc + 2 < ITERS) stage(nc + 2);

    const char* sk = &smem[nc % 3][0];

    if (!grpB) {
      // group A: QK(nc) -> SM(nc) -> PV(nc)
      floatx16 sacc = qk(sk);
      softmax(sacc);
      pv(&smem[3 + (nc & 3)][0]);
    } else {
      // group B: PV(nc-1) -> QK(nc) -> SM(nc)
      if (nc > 0) pv(&smem[3 + ((nc - 1) & 3)][0]);
      floatx16 sacc = qk(sk);
      softmax(sacc);
    }
  }
  if (grpB) pv(&smem[3 + ((ITERS - 1) & 3)][0]);   // V still resident

  // epilogue: column sum across halves, normalize, store bf16 partial + L
  float Lv = Lp + __shfl_xor(Lp, 32);
  const float invL = 1.f / Lv;

  const int pwid = (b * 128 + mt32) * NSPLIT + s;
  unsigned short* pa = pacc + (size_t)pwid * (O_ * 32);
#pragma unroll
  for (int ot = 0; ot < 8; ++ot)
#pragma unroll
    for (int r = 0; r < 16; ++r) {
      const int o = ot * 32 + (r & 3) + 8 * (r >> 2) + 4 * hl;
      pa[o * 32 + m] = f2bf(acc[ot][r] * invL);
    }
  if (hl == 0) pml[pwid * 32 + m] = Lv;
}

// ---------------------------------------------------------------------------
// combine: out[b][o][m0+c] = sum_s w[s][c]*pacc[s][o][c], w = L_s/sum(L)
__global__ __launch_bounds__(256) void combine_kernel(
    const unsigned short* __restrict__ pacc, const float* __restrict__ pml,
    float* __restrict__ out) {
  const int blk = blockIdx.x;   // 512
  const int b   = blk >> 7;
  const int mw  = blk & 127;
  const int o   = threadIdx.x;
  const int base = (b * 128 + mw) * NSPLIT;

  __shared__ float w[NSPLIT][32];
  if (threadIdx.x < 32) {
    const int c = threadIdx.x;
    float L[NSPLIT], sum = 0.f;
#pragma unroll
    for (int sp = 0; sp < NSPLIT; ++sp) {
      L[sp] = pml[(base + sp) * 32 + c];
      sum += L[sp];
    }
    const float inv = 1.f / sum;
#pragma unroll
    for (int sp = 0; sp < NSPLIT; ++sp) w[sp][c] = L[sp] * inv;
  }
  __syncthreads();

  float res[32];
#pragma unroll
  for (int c = 0; c < 32; ++c) res[c] = 0.f;
#pragma unroll
  for (int sp = 0; sp < NSPLIT; ++sp) {
    const unsigned short* pa =
        pacc + (size_t)(base + sp) * (O_ * 32) + o * 32;
#pragma unroll
    for (int c8 = 0; c8 < 4; ++c8) {
      short8 u = *reinterpret_cast<const short8*>(pa + c8 * 8);
#pragma unroll
      for (int i = 0; i < 8; ++i)
        res[c8 * 8 + i] =
            fmaf(w[sp][c8 * 8 + i], bf2f((unsigned short)u[i]), res[c8 * 8 + i]);
    }
  }
  float* ob = out + ((size_t)(b * O_ + o)) * N_ + mw * 32;
#pragma unroll
  for (int c4 = 0; c4 < 8; ++c4) {
    floatx4 v4 = {res[c4 * 4], res[c4 * 4 + 1], res[c4 * 4 + 2], res[c4 * 4 + 3]};
    *reinterpret_cast<floatx4*>(ob + c4 * 4) = v4;
  }
}

// ---------------------------------------------------------------------------
extern "C" void kernel_launch(void* const* d_in, const int* in_sizes, int n_in,
                              void* d_out, int out_size, void* d_ws, size_t ws_size,
                              hipStream_t stream) {
  const float* x  = (const float*)d_in[0];
  const float* Wk = (const float*)d_in[1];
  const float* bk = (const float*)d_in[2];
  const float* Wq = (const float*)d_in[3];
  const float* bq = (const float*)d_in[4];
  const float* W1 = (const float*)d_in[5];
  const float* b1 = (const float*)d_in[6];
  const float* W2 = (const float*)d_in[7];
  const float* b2 = (const float*)d_in[8];
  const float* W3 = (const float*)d_in[9];
  const float* b3 = (const float*)d_in[10];
  float* out = (float*)d_out;

  char* ws = (char*)d_ws;
  const size_t SZ = (size_t)B_ * N_ * H_ * sizeof(unsigned short);  // 8 MiB
  unsigned short* wkbf = (unsigned short*)(ws);            // wk|wq|w1 contiguous
  unsigned short* wqbf = (unsigned short*)(ws + 131072);
  unsigned short* w1bf = (unsigned short*)(ws + 262144);
  unsigned short* w3bf = (unsigned short*)(ws + 393216);
  char* base = ws + 524288;
  unsigned short* kbf  = (unsigned short*)(base);           // persistent (tiled)
  unsigned short* qbf  = (unsigned short*)(base + SZ);      // persistent
  unsigned short* vbf  = (unsigned short*)(base + 2 * SZ);  // persistent (tiled)
  unsigned short* pacc = (unsigned short*)(base + 3 * SZ);  // 32 MB partials
  float*          pml  = (float*)(base + 7 * SZ);           // 256 KB

  prep_w_kernel<<<256, 256, 0, stream>>>(
      Wk, Wq, W1, W3, wkbf, wqbf, w1bf, w3bf);
  fused1_kernel<<<512, 256, 0, stream>>>(x, wkbf, bk, bq, b1, W2, b2,
                                         w3bf, b3, kbf, qbf, vbf);
  attn_kernel<<<256, 512, 0, stream>>>(kbf, qbf, vbf, pacc, pml);
  combine_kernel<<<512, 256, 0, stream>>>(pacc, pml, out);
}

// Round 10
// 220.401 us; speedup vs baseline: 1.0454x; 1.0454x over previous
//
#include <hip/hip_runtime.h>

// ============================================================================
// global_conv_attn: B=4, C=H=O=256, N=4096, GROUPS=32
//
// Pipeline (all bf16-MFMA, fp32 accumulate), 5 launches:
//   prepW: weights fp32->bf16 only (256 blocks, ~1us)
//   gemm1: OP-SPLIT 32x32x16. Block = 32n x 256h x {k,q,v1}. 24 (op,h32)
//          units, 6/wave. x staged once in LDS (17KB).
//   cg2  : FUSED conv+gemm2; v CHUNK-TILED [b][nc][kn2][ot8][hl2][o32][n8]
//   attn : flash, 32x32x16 MFMA, m32/wave, 8 waves/block (512 thr, 256 blks),
//          K ring x3 + V ring x4 (112KB), 2-chunk prefetch, counted vmcnt,
//          wave-group stagger; pacc bf16 partials + pml.
//   comb : merge of 4 splits (~8us)
//
// R16 post-mortem: gemm1+conv+gemm2 mega-fusion REGRESSED +9.2us (absmax
// unchanged -> correct, just slow). 68MB HBM saving (~11us) < ~20us of
// serialization: three resource-disjoint phases (MFMA/VALU/MFMA) behind
// per-block barriers at 4 waves/block recreated the sum-of-pipes wall,
// while split kernels overlap their stalls across blocks at full
// occupancy. R17 = clean revert to R15 (best, 221.2us).
//
// Search state: attn at plain-HIP plateau (4 schedule variants neutral;
// reg wall pins 2 waves/SIMD). gemm1 optimized (-19us). combine-
// elimination (R13 atomics) and cg2-fusion (R16) both measured, both
// regressed. ~120us of total is fixed harness overhead (calibrated by
// traffic-delta sensitivity R14/R15).
//
// MFMA 32x32x16 layouts (gfx950):
//   A row=lane&31, k=(lane>>5)*8+j;  B col=lane&31, same k
//   D col=lane&31, row=(reg&3)+8*(reg>>2)+4*(lane>>5)   [D HW-verified]
// ============================================================================

#define B_ 4
#define C_ 256
#define H_ 256
#define O_ 256
#define N_ 4096
#define NSPLIT 4
#define SPAN (N_ / NSPLIT)     // 1024
#define ITERS (SPAN / 32)      // 32

typedef short short8 __attribute__((ext_vector_type(8)));
typedef float floatx4 __attribute__((ext_vector_type(4)));
typedef float floatx16 __attribute__((ext_vector_type(16)));
typedef unsigned uint2v __attribute__((ext_vector_type(2)));

__device__ __forceinline__ unsigned short f2bf(float f) {
  unsigned u = __float_as_uint(f);
  u = (u + 0x7fffu + ((u >> 16) & 1u)) >> 16;   // RNE
  return (unsigned short)u;
}
__device__ __forceinline__ float bf2f(unsigned short u) {
  return __uint_as_float(((unsigned)u) << 16);
}
__device__ __forceinline__ floatx16 mfma32(short8 a, short8 b, floatx16 c) {
  return __builtin_amdgcn_mfma_f32_32x32x16_bf16(a, b, c, 0, 0, 0);
}
// pack two floats -> (bf16(a) | bf16(b)<<16), round-half-up (2 add + 1 perm)
__device__ __forceinline__ unsigned pack2bf(float a, float b) {
  return __builtin_amdgcn_perm(__float_as_uint(b) + 0x8000u,
                               __float_as_uint(a) + 0x8000u, 0x07060302u);
}

// ---------------------------------------------------------------------------
// weight prep only: fp32 -> bf16 for Wk,Wq,W1 (contiguous) and W3.
__global__ __launch_bounds__(256) void prep_w_kernel(
    const float* __restrict__ Wk, const float* __restrict__ Wq,
    const float* __restrict__ W1, const float* __restrict__ W3,
    unsigned short* __restrict__ wk, unsigned short* __restrict__ wq,
    unsigned short* __restrict__ w1, unsigned short* __restrict__ w3) {
  const int i = blockIdx.x * 256 + threadIdx.x;    // 65536
  wk[i] = f2bf(Wk[i]);
  wq[i] = f2bf(Wq[i]);
  w1[i] = f2bf(W1[i]);
  w3[i] = f2bf(W3[i]);
}

// ---------------------------------------------------------------------------
// gemm1 v2 (op-split): D[n][h] = sum_c x_bf[n][c]*W[h][c] + bias, for
// W in {Wk,Wq,W1} (contiguous at wk + op*65536).
// Block (512 total) = (b, n-chunk32): 32 n x 256 c staged in LDS as bf16
// (bit-identical f2bf), 4 waves x 6 units; unit = (op, tt32) of 24.
// mfma32: A = x rows (n = lane&31 local), B = W rows as cols
// (h = tt*32 + lane&31), K = 16/step x 16 steps.
__global__ __launch_bounds__(256) void gemm1_kernel(
    const float* __restrict__ x,
    const unsigned short* __restrict__ wk,   // wk|wq|w1 contiguous
    const float* __restrict__ bk, const float* __restrict__ bq,
    const float* __restrict__ b1,
    unsigned short* __restrict__ ko, unsigned short* __restrict__ qo,
    unsigned short* __restrict__ v1o) {
  __shared__ unsigned short xL[32][264];   // 16.9 KB, row pad 8

  const int blk  = blockIdx.x;     // 512
  const int b    = blk >> 7;
  const int nc   = blk & 127;
  const int n032 = nc * 32;
  const int t    = threadIdx.x;

  // stage x[b][c][n032..+31] -> xL[n][c] bf16; 8 segments x 128B per instr
  {
    const int c0 = t >> 3;
    const int nq = t & 7;
    const float* xb = x + ((size_t)b * C_) * N_ + n032 + nq * 4;
#pragma unroll
    for (int i = 0; i < 8; ++i) {
      const int c = c0 + i * 32;
      const floatx4 v = *reinterpret_cast<const floatx4*>(xb + (size_t)c * N_);
#pragma unroll
      for (int j = 0; j < 4; ++j) xL[nq * 4 + j][c] = f2bf(v[j]);
    }
  }
  __syncthreads();

  const int ln  = t & 63;
  const int wv  = t >> 6;      // 0..3
  const int m32 = ln & 31;
  const int hl  = ln >> 5;

  // 6 units per wave: gu = wv*6+u in [0,24); op = gu>>3, tt = gu&7
  int   uoff[6];               // element offset into wk for B-frag row
  float ubias[6];
  int   uop[6], utt[6];
#pragma unroll
  for (int u = 0; u < 6; ++u) {
    const int gu = wv * 6 + u;
    const int op = gu >> 3;
    const int tt = gu & 7;
    uop[u] = op;
    utt[u] = tt;
    uoff[u] = op * 65536 + (tt * 32 + m32) * 256 + hl * 8;
    const float* bp = (op == 0) ? bk : ((op == 1) ? bq : b1);
    ubias[u] = bp[tt * 32 + m32];
  }

  floatx16 acc[6];
#pragma unroll
  for (int u = 0; u < 6; ++u)
#pragma unroll
    for (int r = 0; r < 16; ++r) acc[u][r] = 0.f;

#pragma unroll
  for (int ks = 0; ks < 16; ++ks) {
    short8 af = *reinterpret_cast<const short8*>(&xL[m32][ks * 16 + hl * 8]);
#pragma unroll
    for (int u = 0; u < 6; ++u) {
      short8 bf = *reinterpret_cast<const short8*>(wk + uoff[u] + ks * 16);
      acc[u] = mfma32(af, bf, acc[u]);
    }
  }

  // stores: D col = lane&31 -> h-col; row = crow(r,hl) -> local n
#pragma unroll
  for (int u = 0; u < 6; ++u) {
    const int h = utt[u] * 32 + m32;
    if (uop[u] == 0) {
      // k chunk-tiled: elem = (h>>4)*512 + ((h>>3)&1)*256 + nl*8 + (h&7)
      unsigned short* kb = ko + ((size_t)(b * 128 + nc)) * 8192;
      const int eh = (h >> 4) * 512 + ((h >> 3) & 1) * 256 + (h & 7);
#pragma unroll
      for (int r = 0; r < 16; ++r) {
        const int nl = (r & 3) + 8 * (r >> 2) + 4 * hl;
        kb[eh + nl * 8] = f2bf(acc[u][r] + ubias[u]);
      }
    } else {
      unsigned short* o = (uop[u] == 1) ? qo : v1o;
#pragma unroll
      for (int r = 0; r < 16; ++r) {
        const int n = n032 + (r & 3) + 8 * (r >> 2) + 4 * hl;
        o[((size_t)(b * N_ + n)) * H_ + h] = f2bf(acc[u][r] + ubias[u]);
      }
    }
  }
}

// ---------------------------------------------------------------------------
// FUSED conv + gemm2. Block = (b, n-span32). v2 tile lives only in LDS [n][h].
// v -> chunk-tiled [b][nc][kn2][ot8][hl2][o32][n8] (linear-lane granules).
__global__ __launch_bounds__(256) void convgemm2_kernel(
    const unsigned short* __restrict__ v1, const float* __restrict__ W2,
    const float* __restrict__ b2, const unsigned short* __restrict__ w3,
    const float* __restrict__ b3, unsigned short* __restrict__ vo) {
  __shared__ unsigned short v2L[32][264];   // 16.5 KB, row pad 8

  const int h   = threadIdx.x;
  const int blk = blockIdx.x;        // 512
  const int b   = blk >> 7;
  const int nc  = blk & 127;
  const int n0  = nc * 32;
  const int g8  = h & ~7;

  {  // conv: sliding window, thread = h
    float w[24];
#pragma unroll
    for (int i = 0; i < 24; ++i) w[i] = W2[h * 24 + i];
    const float bias = b2[h];
    const unsigned short* vb = v1 + (size_t)b * (N_ * H_) + g8;

    float fp[8], fc[8], fn[8];
    if (n0 == 0) {
#pragma unroll
      for (int i = 0; i < 8; ++i) fp[i] = 0.f;
    } else {
      short8 u = *reinterpret_cast<const short8*>(vb + (size_t)(n0 - 1) * H_);
#pragma unroll
      for (int i = 0; i < 8; ++i) fp[i] = bf2f((unsigned short)u[i]);
    }
    {
      short8 u = *reinterpret_cast<const short8*>(vb + (size_t)n0 * H_);
#pragma unroll
      for (int i = 0; i < 8; ++i) fc[i] = bf2f((unsigned short)u[i]);
    }
#pragma unroll 1
    for (int ns = 0; ns < 32; ++ns) {
      const int n = n0 + ns;
      if (n + 1 < N_) {
        short8 u = *reinterpret_cast<const short8*>(vb + (size_t)(n + 1) * H_);
#pragma unroll
        for (int i = 0; i < 8; ++i) fn[i] = bf2f((unsigned short)u[i]);
      } else {
#pragma unroll
        for (int i = 0; i < 8; ++i) fn[i] = 0.f;
      }
      float a = bias;
#pragma unroll
      for (int i = 0; i < 8; ++i)
        a += w[i * 3] * fp[i] + w[i * 3 + 1] * fc[i] + w[i * 3 + 2] * fn[i];
      v2L[ns][h] = f2bf(fmaxf(a, 0.f));
#pragma unroll
      for (int i = 0; i < 8; ++i) { fp[i] = fc[i]; fc[i] = fn[i]; }
    }
  }
  __syncthreads();

  // gemm2: wave wv handles o-range wv*64..+63.  A = W3 rows o, B = v2L cols n.
  const int ln = threadIdx.x & 63;
  const int wv = threadIdx.x >> 6;
  const int m  = ln & 31;
  const int hl = ln >> 5;

  floatx16 acc2[2];
#pragma unroll
  for (int ot = 0; ot < 2; ++ot)
#pragma unroll
    for (int r = 0; r < 16; ++r) acc2[ot][r] = 0.f;

#pragma unroll
  for (int ks = 0; ks < 16; ++ks) {
    short8 bfr = *reinterpret_cast<const short8*>(&v2L[m][ks * 16 + hl * 8]);
#pragma unroll
    for (int ot = 0; ot < 2; ++ot) {
      const int o0 = wv * 64 + ot * 32;
      short8 afr = *reinterpret_cast<const short8*>(
          w3 + (o0 + m) * H_ + ks * 16 + hl * 8);
      acc2[ot] = mfma32(afr, bfr, acc2[ot]);
    }
  }

  // D rows = o, cols = n (lane&31). linear-lane chunk-tiled V store:
  // elem-in-kn-block = (o>>5)*512 + ((n&15)>>3)*256 + (o&31)*8 + (n&7)
  const int kn = (m >> 4) & 1;
  const int nl = m & 15;
  unsigned short* vkn = vo + ((size_t)(b * 128 + nc) * 2 + kn) * 4096;
#pragma unroll
  for (int ot = 0; ot < 2; ++ot)
#pragma unroll
    for (int r = 0; r < 16; ++r) {
      const int o = wv * 64 + ot * 32 + (r & 3) + 8 * (r >> 2) + 4 * hl;
      vkn[(o >> 5) * 512 + (nl >> 3) * 256 + (o & 31) * 8 + (nl & 7)] =
          f2bf(acc2[ot][r] + b3[o]);
    }
}

// ---------------------------------------------------------------------------
// attn: m32/wave, 8 waves (512 thr) share staged K/V chunks, 256 blocks.
// K ring x3 + V ring x4 (112 KB), 2-chunk prefetch, counted vmcnt(4) + raw
// s_barrier (vmcnt(0) only at last). Wave-group stagger (grpA QK->SM->PV;
// grpB PV(prev)->QK->SM). Epilogue: normalized bf16 partials (pacc) + L.
__global__ __launch_bounds__(512, 2) void attn_kernel(
    const unsigned short* __restrict__ kbf, const unsigned short* __restrict__ qbf,
    const unsigned short* __restrict__ vbf,
    unsigned short* __restrict__ pacc, float* __restrict__ pml) {
  __shared__ __attribute__((aligned(16))) char smem[7][16384];   // 112 KB

  const int tid = threadIdx.x;
  const int ln  = tid & 63;
  const int wv  = tid >> 6;            // 0..7
  const int gid = blockIdx.x;          // 256
  const int b   = gid & 3;             // low bits -> XCD spread of (b,s)
  const int s   = (gid >> 2) & 3;
  const int mt256 = gid >> 4;          // 0..15
  const int mt32  = mt256 * 8 + wv;    // 0..127
  const int m0  = mt32 * 32;
  const int m   = ln & 31;
  const int hl  = ln >> 5;
  const bool grpB = (wv >= 4);
  // linear-lane fragment base: granule (row,hl) pre-placed at byte
  // hl*512+row*16 in each 1KB block -> lane ln reads byte ln*16.
  const int lane_base = ln * 16;

  // Q frags: col m = lane&31, k = ks*16 + hl*8 + j
  const unsigned short* qrow = qbf + ((size_t)b * N_ + m0 + m) * H_ + hl * 8;
  short8 qf[16];
#pragma unroll
  for (int ks = 0; ks < 16; ++ks)
    qf[ks] = *reinterpret_cast<const short8*>(qrow + ks * 16);

  floatx16 acc[8];
#pragma unroll
  for (int t = 0; t < 8; ++t)
#pragma unroll
    for (int r = 0; r < 16; ++r) acc[t][r] = 0.f;
  float Lp = 0.f;

  const size_t row0 = (size_t)(b * 128 + s * 32);

  // stage chunk nc: K -> slot nc%3, V -> slot 3 + (nc&3).
  // 512 lanes x 2 x 16B covers 16 KB each of K and V -> 4 loads/lane/chunk.
  auto stage = [&](int nc) {
    const char* kg = (const char*)(kbf + (row0 + nc) * 8192);
    const char* vg = (const char*)(vbf + (row0 + nc) * 8192);
    char* lk = &smem[nc % 3][0];
    char* lv = &smem[3 + (nc & 3)][0];
#pragma unroll
    for (int j = 0; j < 2; ++j) {
      const int ofs = j * 8192 + tid * 16;
      __builtin_amdgcn_global_load_lds(
          (const __attribute__((address_space(1))) void*)(kg + ofs),
          (__attribute__((address_space(3))) void*)(lk + ofs), 16, 0, 0);
      __builtin_amdgcn_global_load_lds(
          (const __attribute__((address_space(1))) void*)(vg + ofs),
          (__attribute__((address_space(3))) void*)(lv + ofs), 16, 0, 0);
    }
  };

  short8 pf0, pf1;   // P fragments (loop-carried across iters for grpB)

  // QK: S tile 32n x 32m, A = K rows from LDS, B = qf
  auto qk = [&](const char* sk) -> floatx16 {
    floatx16 sacc;
#pragma unroll
    for (int r = 0; r < 16; ++r) sacc[r] = 0.f;
    __builtin_amdgcn_s_setprio(1);
#pragma unroll
    for (int ks = 0; ks < 16; ++ks) {
      short8 kf = *reinterpret_cast<const short8*>(sk + lane_base + ks * 1024);
      sacc = mfma32(kf, qf[ks], sacc);
    }
    __builtin_amdgcn_s_setprio(0);
    return sacc;
  };
  // PV: D[o][m] += V-rows (A, from LDS) * P (B, regs)
  auto pv = [&](const char* sv) {
    __builtin_amdgcn_s_setprio(1);
#pragma unroll
    for (int ot = 0; ot < 8; ++ot) {
      short8 vf0 = *reinterpret_cast<const short8*>(sv + lane_base + ot * 1024);
      short8 vf1 = *reinterpret_cast<const short8*>(
          sv + lane_base + 8192 + ot * 1024);
      acc[ot] = mfma32(vf0, pf0, acc[ot]);
      acc[ot] = mfma32(vf1, pf1, acc[ot]);
    }
    __builtin_amdgcn_s_setprio(0);
  };
  // SM: P = exp(S), pack adjacent-n pairs, permlane32 relayout -> pf0/pf1
  auto softmax = [&](floatx16 sacc) {
#if __has_builtin(__builtin_amdgcn_permlane32_swap)
    unsigned d[8];
#pragma unroll
    for (int i = 0; i < 8; ++i) {
      const float a = __expf(sacc[2 * i]);
      const float bb = __expf(sacc[2 * i + 1]);
      Lp += a + bb;
      d[i] = pack2bf(a, bb);
    }
#pragma unroll
    for (int g = 0; g < 2; ++g) {
      uint2v r0 = __builtin_amdgcn_permlane32_swap(d[4 * g + 0], d[4 * g + 2],
                                                   false, false);
      uint2v r1 = __builtin_amdgcn_permlane32_swap(d[4 * g + 1], d[4 * g + 3],
                                                   false, false);
      d[4 * g + 0] = r0.x; d[4 * g + 2] = r0.y;
      d[4 * g + 1] = r1.x; d[4 * g + 3] = r1.y;
    }
    union { unsigned u[4]; short8 s8; } c0, c1;
    c0.u[0] = d[0]; c0.u[1] = d[1]; c0.u[2] = d[2]; c0.u[3] = d[3];
    c1.u[0] = d[4]; c1.u[1] = d[5]; c1.u[2] = d[6]; c1.u[3] = d[7];
    pf0 = c0.s8;
    pf1 = c1.s8;
#else
    // fallback: pack (r, r+4) pairs + 16 bpermute relayout (R6 path)
    float pv_[16];
#pragma unroll
    for (int r = 0; r < 16; ++r) { pv_[r] = __expf(sacc[r]); Lp += pv_[r]; }
    unsigned wpk[8];
#pragma unroll
    for (int r4 = 0; r4 < 4; ++r4) {
      wpk[r4]     = pack2bf(pv_[r4], pv_[r4 + 4]);
      wpk[r4 + 4] = pack2bf(pv_[r4 + 8], pv_[r4 + 12]);
    }
    const int hlsh = hl * 16;
#pragma unroll
    for (int j = 0; j < 8; ++j) {
      const int srcLane = m + ((j >> 2) << 5);
      const int u0 = __shfl((int)wpk[j & 3],       srcLane);
      const int u1 = __shfl((int)wpk[(j & 3) + 4], srcLane);
      pf0[j] = (short)((unsigned)u0 >> hlsh);
      pf1[j] = (short)((unsigned)u1 >> hlsh);
    }
#endif
  };

  stage(0);
  stage(1);

#pragma unroll 1
  for (int nc = 0; nc < ITERS; ++nc) {
    // counted drain: chunk nc landed; chunk nc+1's 4 loads may stay in
    // flight across the barrier. Full drain only on the last iter.
    if (nc + 1 < ITERS) {
      asm volatile("s_waitcnt vmcnt(4)\n\ts_barrier" ::: "memory");
    } else {
      asm volatile("s_waitcnt vmcnt(0)\n\ts_barrier" ::: "memory");
    }
    __builtin_amdgcn_sched_barrier(0);
    if (nc + 2 < ITERS) stage(nc + 2);

    const char* sk = &smem[nc % 3][0];

    if (!grpB) {
      // group A: QK(nc) -> SM(nc) -> PV(nc)
      floatx16 sacc = qk(sk);
      softmax(sacc);
      pv(&smem[3 + (nc & 3)][0]);
    } else {
      // group B: PV(nc-1) -> QK(nc) -> SM(nc)
      if (nc > 0) pv(&smem[3 + ((nc - 1) & 3)][0]);
      floatx16 sacc = qk(sk);
      softmax(sacc);
    }
  }
  if (grpB) pv(&smem[3 + ((ITERS - 1) & 3)][0]);   // V still resident

  // epilogue: column sum across halves, normalize, store bf16 partial + L
  float Lv = Lp + __shfl_xor(Lp, 32);
  const float invL = 1.f / Lv;

  const int pwid = (b * 128 + mt32) * NSPLIT + s;
  unsigned short* pa = pacc + (size_t)pwid * (O_ * 32);
#pragma unroll
  for (int ot = 0; ot < 8; ++ot)
#pragma unroll
    for (int r = 0; r < 16; ++r) {
      const int o = ot * 32 + (r & 3) + 8 * (r >> 2) + 4 * hl;
      pa[o * 32 + m] = f2bf(acc[ot][r] * invL);
    }
  if (hl == 0) pml[pwid * 32 + m] = Lv;
}

// ---------------------------------------------------------------------------
// combine: out[b][o][m0+c] = sum_s w[s][c]*pacc[s][o][c], w = L_s/sum(L)
__global__ __launch_bounds__(256) void combine_kernel(
    const unsigned short* __restrict__ pacc, const float* __restrict__ pml,
    float* __restrict__ out) {
  const int blk = blockIdx.x;   // 512
  const int b   = blk >> 7;
  const int mw  = blk & 127;
  const int o   = threadIdx.x;
  const int base = (b * 128 + mw) * NSPLIT;

  __shared__ float w[NSPLIT][32];
  if (threadIdx.x < 32) {
    const int c = threadIdx.x;
    float L[NSPLIT], sum = 0.f;
#pragma unroll
    for (int sp = 0; sp < NSPLIT; ++sp) {
      L[sp] = pml[(base + sp) * 32 + c];
      sum += L[sp];
    }
    const float inv = 1.f / sum;
#pragma unroll
    for (int sp = 0; sp < NSPLIT; ++sp) w[sp][c] = L[sp] * inv;
  }
  __syncthreads();

  float res[32];
#pragma unroll
  for (int c = 0; c < 32; ++c) res[c] = 0.f;
#pragma unroll
  for (int sp = 0; sp < NSPLIT; ++sp) {
    const unsigned short* pa =
        pacc + (size_t)(base + sp) * (O_ * 32) + o * 32;
#pragma unroll
    for (int c8 = 0; c8 < 4; ++c8) {
      short8 u = *reinterpret_cast<const short8*>(pa + c8 * 8);
#pragma unroll
      for (int i = 0; i < 8; ++i)
        res[c8 * 8 + i] =
            fmaf(w[sp][c8 * 8 + i], bf2f((unsigned short)u[i]), res[c8 * 8 + i]);
    }
  }
  float* ob = out + ((size_t)(b * O_ + o)) * N_ + mw * 32;
#pragma unroll
  for (int c4 = 0; c4 < 8; ++c4) {
    floatx4 v4 = {res[c4 * 4], res[c4 * 4 + 1], res[c4 * 4 + 2], res[c4 * 4 + 3]};
    *reinterpret_cast<floatx4*>(ob + c4 * 4) = v4;
  }
}

// ---------------------------------------------------------------------------
extern "C" void kernel_launch(void* const* d_in, const int* in_sizes, int n_in,
                              void* d_out, int out_size, void* d_ws, size_t ws_size,
                              hipStream_t stream) {
  const float* x  = (const float*)d_in[0];
  const float* Wk = (const float*)d_in[1];
  const float* bk = (const float*)d_in[2];
  const float* Wq = (const float*)d_in[3];
  const float* bq = (const float*)d_in[4];
  const float* W1 = (const float*)d_in[5];
  const float* b1 = (const float*)d_in[6];
  const float* W2 = (const float*)d_in[7];
  const float* b2 = (const float*)d_in[8];
  const float* W3 = (const float*)d_in[9];
  const float* b3 = (const float*)d_in[10];
  float* out = (float*)d_out;

  char* ws = (char*)d_ws;
  const size_t SZ = (size_t)B_ * N_ * H_ * sizeof(unsigned short);  // 8 MiB
  unsigned short* wkbf = (unsigned short*)(ws);            // wk|wq|w1 contiguous
  unsigned short* wqbf = (unsigned short*)(ws + 131072);
  unsigned short* w1bf = (unsigned short*)(ws + 262144);
  unsigned short* w3bf = (unsigned short*)(ws + 393216);
  char* base = ws + 524288;
  unsigned short* kbf  = (unsigned short*)(base);           // persistent (tiled)
  unsigned short* qbf  = (unsigned short*)(base + SZ);      // persistent
  unsigned short* vbf  = (unsigned short*)(base + 2 * SZ);  // persistent (tiled)
  unsigned short* v1bf = (unsigned short*)(base + 3 * SZ);  // dead after cg2
  // partials (32 MB = 4*SZ) overlap v1bf + 3 more SZ
  unsigned short* pacc = (unsigned short*)(base + 3 * SZ);
  float*          pml  = (float*)(base + 7 * SZ);           // 256 KB

  prep_w_kernel<<<256, 256, 0, stream>>>(
      Wk, Wq, W1, W3, wkbf, wqbf, w1bf, w3bf);
  gemm1_kernel<<<512, 256, 0, stream>>>(x, wkbf, bk, bq, b1,
                                        kbf, qbf, v1bf);
  convgemm2_kernel<<<512, 256, 0, stream>>>(v1bf, W2, b2, w3bf, b3, vbf);
  attn_kernel<<<256, 512, 0, stream>>>(kbf, qbf, vbf, pacc, pml);
  combine_kernel<<<512, 256, 0, stream>>>(pacc, pml, out);
}